// Round 1
// baseline (14140.269 us; speedup 1.0000x reference)
//
#include <hip/hip_runtime.h>

#define BSZ   64
#define SEQL  100
#define DIM   512
#define L1P   101
#define NCOLS 6464     // BSZ*L1P
#define NROWS 6400     // BSZ*SEQL
#define D3    1536
#define MASKV -10000.0f

__device__ __forceinline__ float sigm(float x)  { return 1.f / (1.f + __expf(-x)); }
__device__ __forceinline__ float ftanh(float x) { float e = __expf(2.f * x); return 1.f - 2.f / (e + 1.f); }

// ---------------- K0: zero the loss accumulators (ws re-poisoned each call) ----
__global__ void zero_acc(float* acc) { acc[0] = 0.f; acc[1] = 0.f; }

// ---------------- K1: gather score_embs[k][:] = id_emb[ids[k]][:] --------------
__global__ void gather_embs(const int* __restrict__ ids, const float* __restrict__ emb,
                            float* __restrict__ score)
{
    int idx = blockIdx.x * 256 + threadIdx.x;      // 6464*128 total
    int row = idx >> 7, c4 = idx & 127;
    int id = ids[row];
    *(float4*)&score[(size_t)row * DIM + c4 * 4] =
        *(const float4*)&emb[(size_t)id * DIM + c4 * 4];
}

// ---------------- K2: debias + col_valid --------------------------------------
__global__ void aux_kernel(const int* __restrict__ ids, const float* __restrict__ pop,
                           const int* __restrict__ lmask,
                           float* __restrict__ debias, int* __restrict__ colv)
{
    int k = blockIdx.x * 256 + threadIdx.x;
    if (k >= NCOLS) return;
    int id = ids[k];
    debias[k] = __logf(pop[id]);
    int j = k % L1P;
    colv[k] = (j == SEQL) ? 1 : lmask[(k / L1P) * SEQL + j];
}

// ---------------- K3: reject[i][k] = ids[k] in sample i's list ----------------
__global__ void build_reject(const int* __restrict__ ids, unsigned char* __restrict__ reject)
{
    __shared__ int s_ids[L1P];
    int i = blockIdx.y;
    int tid = threadIdx.x;
    if (tid < L1P) s_ids[tid] = ids[i * L1P + tid];
    __syncthreads();
    int k = blockIdx.x * 256 + tid;
    if (k >= NCOLS) return;
    int myid = ids[k];
    int rej = 0;
    for (int j = 0; j < L1P; ++j) rej |= (myid == s_ids[j]);
    reject[(size_t)i * NCOLS + k] = (unsigned char)rej;
}

// ---------------- K4: gates_x = A @ W_ih + b_ih  (A rows remapped) ------------
// C tile 64x64, 256 threads, 4x4 per thread, K-tile 16.
__global__ void gates_gemm(const float* __restrict__ score, const float* __restrict__ W_ih,
                           const float* __restrict__ b_ih, float* __restrict__ gates)
{
    __shared__ float As[16][64];   // [kk][row]
    __shared__ float Bs[16][64];   // [kk][col]
    int tid = threadIdx.x;
    int n0 = blockIdx.x * 64, r0 = blockIdx.y * 64;
    int tx = tid & 15, ty = tid >> 4;

    int arow = tid >> 2, akc = tid & 3;
    int gr = r0 + arow;
    const float* Arow = score + (size_t)((gr / SEQL) * L1P + (gr % SEQL)) * DIM;
    int bkk = tid >> 4, bnc = tid & 15;

    float acc[4][4] = {};
    for (int k0 = 0; k0 < DIM; k0 += 16) {
        float4 av = *(const float4*)&Arow[k0 + akc * 4];
        As[akc * 4 + 0][arow] = av.x;
        As[akc * 4 + 1][arow] = av.y;
        As[akc * 4 + 2][arow] = av.z;
        As[akc * 4 + 3][arow] = av.w;
        *(float4*)&Bs[bkk][bnc * 4] =
            *(const float4*)&W_ih[(size_t)(k0 + bkk) * D3 + n0 + bnc * 4];
        __syncthreads();
#pragma unroll
        for (int kk = 0; kk < 16; ++kk) {
            float4 a = *(float4*)&As[kk][ty * 4];
            float4 b = *(float4*)&Bs[kk][tx * 4];
            float aa[4] = {a.x, a.y, a.z, a.w};
            float bb[4] = {b.x, b.y, b.z, b.w};
#pragma unroll
            for (int u = 0; u < 4; ++u)
#pragma unroll
                for (int v = 0; v < 4; ++v)
                    acc[u][v] = fmaf(aa[u], bb[v], acc[u][v]);
        }
        __syncthreads();
    }
    float4 bv = *(const float4*)&b_ih[n0 + tx * 4];
#pragma unroll
    for (int u = 0; u < 4; ++u) {
        int rr = r0 + ty * 4 + u;
        float4 o;
        o.x = acc[u][0] + bv.x; o.y = acc[u][1] + bv.y;
        o.z = acc[u][2] + bv.z; o.w = acc[u][3] + bv.w;
        *(float4*)&gates[(size_t)rr * D3 + n0 + tx * 4] = o;
    }
}

// ---------------- K5: one GRU step (launched 100x) ----------------------------
// 256 blocks x 128 threads: b = blockIdx>>2, d = (blockIdx&3)*128 + tid.
__global__ void gru_step(const float* __restrict__ W_hh, const float* __restrict__ b_hh,
                         const float* __restrict__ gates, float* __restrict__ prec, int t)
{
    __shared__ float hs[DIM];
    int b = blockIdx.x >> 2;
    int d = ((blockIdx.x & 3) << 7) + threadIdx.x;
    for (int idx = threadIdx.x; idx < DIM; idx += 128)
        hs[idx] = (t == 0) ? 0.f : prec[(size_t)(b * SEQL + t - 1) * DIM + idx];
    __syncthreads();

    float hr = b_hh[d], hz = b_hh[DIM + d], hn = b_hh[2 * DIM + d];
#pragma unroll 4
    for (int k = 0; k < DIM; ++k) {
        float hv = hs[k];
        const float* w = W_hh + (size_t)k * D3;
        hr = fmaf(hv, w[d], hr);
        hz = fmaf(hv, w[DIM + d], hz);
        hn = fmaf(hv, w[2 * DIM + d], hn);
    }
    const float* gx = gates + (size_t)(b * SEQL + t) * D3;
    float r = sigm(gx[d] + hr);
    float z = sigm(gx[DIM + d] + hz);
    float n = ftanh(gx[2 * DIM + d] + r * hn);
    float hp = hs[d];
    prec[(size_t)(b * SEQL + t) * DIM + d] = (1.f - z) * n + z * hp;
}

// ---------------- K6: fused logits + masking + online logsumexp + NLL ---------
// Block = 16 rows; thread (rs,cs): rs=tid>>4 row, cs=tid&15 col-phase.
__global__ void logits_lse(const float* __restrict__ prec, const float* __restrict__ emb,
                           const float* __restrict__ debias, const int* __restrict__ colv,
                           const unsigned char* __restrict__ reject,
                           const int* __restrict__ lmask, float* __restrict__ acc)
{
    __shared__ float ps[16][DIM];
    __shared__ float label_s[16];
    int tid = threadIdx.x;
    int r0 = blockIdx.x * 16;
    for (int idx = tid; idx < 16 * 128; idx += 256) {
        int row = idx >> 7, c4 = idx & 127;
        *(float4*)&ps[row][c4 * 4] = *(const float4*)&prec[(size_t)(r0 + row) * DIM + c4 * 4];
    }
    __syncthreads();

    int cs = tid & 15, rs = tid >> 4;
    int r = r0 + rs, i = r / SEQL, j = r % SEQL;
    int tgt = i * L1P + j + 1;
    const unsigned char* rej = reject + (size_t)i * NCOLS;
    const float* pr = ps[rs];

    float m = -1e30f, s = 0.f;
    for (int k = cs; k < NCOLS; k += 16) {
        const float4* eb = (const float4*)(emb + (size_t)k * DIM);
        float dot = 0.f;
#pragma unroll 8
        for (int c = 0; c < 128; ++c) {
            float4 a = *(const float4*)&pr[c * 4];
            float4 b = eb[c];
            dot = fmaf(a.x, b.x, dot);
            dot = fmaf(a.y, b.y, dot);
            dot = fmaf(a.z, b.z, dot);
            dot = fmaf(a.w, b.w, dot);
        }
        float l = dot - debias[k];
        bool masked = (colv[k] == 0) || (rej[k] && k != tgt);
        l = masked ? MASKV : l;
        if (k == tgt) label_s[rs] = l;
        float mn = fmaxf(m, l);
        s = s * __expf(m - mn) + __expf(l - mn);
        m = mn;
    }
    // reduce (m,s) across the 16 lanes sharing a row
#pragma unroll
    for (int off = 1; off < 16; off <<= 1) {
        float m2 = __shfl_xor(m, off);
        float s2 = __shfl_xor(s, off);
        float mn = fmaxf(m, m2);
        s = s * __expf(m - mn) + s2 * __expf(m2 - mn);
        m = mn;
    }
    __syncthreads();
    if (cs == 0) {
        float label = label_s[rs];
        float nll = m + __logf(s) - label;
        float w = (lmask[r] != 0) ? 1.f : 0.f;
        atomicAdd(&acc[0], nll * w);
        atomicAdd(&acc[1], w);
    }
}

// ---------------- K7: finalize -------------------------------------------------
__global__ void finalize(const float* __restrict__ acc, float* __restrict__ out)
{
    out[0] = acc[0] / fmaxf(acc[1], 1.f);
}

extern "C" void kernel_launch(void* const* d_in, const int* in_sizes, int n_in,
                              void* d_out, int out_size, void* d_ws, size_t ws_size,
                              hipStream_t stream)
{
    const int*   ids   = (const int*)d_in[0];
    const int*   lmask = (const int*)d_in[1];
    const float* pop   = (const float*)d_in[2];
    const float* emb   = (const float*)d_in[3];
    const float* W_ih  = (const float*)d_in[4];
    const float* W_hh  = (const float*)d_in[5];
    const float* b_ih  = (const float*)d_in[6];
    const float* b_hh  = (const float*)d_in[7];
    float* out = (float*)d_out;

    // workspace layout (all 16B-aligned): total ~66.2 MB
    float* score  = (float*)d_ws;                                  // 6464*512 f32
    float* debias = score + (size_t)NCOLS * DIM;                   // 6464 f32
    int*   colv   = (int*)(debias + NCOLS);                        // 6464 i32
    unsigned char* rej = (unsigned char*)(colv + NCOLS);           // 64*6464 u8
    float* gates  = (float*)(rej + (size_t)BSZ * NCOLS);           // 6400*1536 f32
    float* prec   = gates + (size_t)NROWS * D3;                    // 6400*512 f32
    float* acc    = prec + (size_t)NROWS * DIM;                    // 2 f32

    zero_acc<<<1, 1, 0, stream>>>(acc);
    gather_embs<<<(NCOLS * 128) / 256, 256, 0, stream>>>(ids, emb, score);
    aux_kernel<<<(NCOLS + 255) / 256, 256, 0, stream>>>(ids, pop, lmask, debias, colv);
    build_reject<<<dim3((NCOLS + 255) / 256, BSZ), 256, 0, stream>>>(ids, rej);
    gates_gemm<<<dim3(D3 / 64, NROWS / 64), 256, 0, stream>>>(score, W_ih, b_ih, gates);
    for (int t = 0; t < SEQL; ++t)
        gru_step<<<256, 128, 0, stream>>>(W_hh, b_hh, gates, prec, t);
    logits_lse<<<NROWS / 16, 256, 0, stream>>>(prec, score, debias, colv, rej, lmask, acc);
    finalize<<<1, 1, 0, stream>>>(acc, out);
}

// Round 3
// 5022.371 us; speedup vs baseline: 2.8155x; 2.8155x over previous
//
#include <hip/hip_runtime.h>
#include <hip/hip_bf16.h>

#define BSZ   64
#define SEQL  100
#define DIM   512
#define L1P   101
#define NCOLS 6464     // BSZ*L1P
#define NROWS 6400     // BSZ*SEQL
#define D3    1536
#define MASKV -10000.0f
#define M0    16.0f    // fixed softmax reference: logits provably < ~10

typedef __attribute__((ext_vector_type(8))) short bf16x8;
typedef __attribute__((ext_vector_type(4))) float f32x4;

__device__ __forceinline__ float sigm(float x)  { return 1.f / (1.f + __expf(-x)); }
__device__ __forceinline__ float ftanh(float x) { float e = __expf(2.f * x); return 1.f - 2.f / (e + 1.f); }
__device__ __forceinline__ ushort f2bf(float x) {
    __hip_bfloat16 b = __float2bfloat16(x);
    return *(ushort*)&b;
}
__device__ __forceinline__ float bf2f(ushort u) {
    return __uint_as_float(((unsigned)u) << 16);
}

// ---------------- K0: init workspace (s_glob, acc, prec16 pad rows) -----------
__global__ void init_ws(float* s_glob, float* acc, unsigned* prec_pad)
{
    int t = blockIdx.x * 256 + threadIdx.x;     // 6400 threads
    if (t < NROWS) s_glob[t] = 0.f;
    if (t < 2) acc[t] = 0.f;
    if (t < 4096) prec_pad[t] = 0;              // rows 6400..6415 of prec16
}

// ---------------- K1: gather score16[k][:] = bf16(id_emb[ids[k]][:]) ----------
__global__ void gather_embs(const int* __restrict__ ids, const float* __restrict__ emb,
                            ushort* __restrict__ score16)
{
    int idx = blockIdx.x * 256 + threadIdx.x;   // 6464*128
    int row = idx >> 7, c4 = idx & 127;
    int id = ids[row];
    float4 v = *(const float4*)&emb[(size_t)id * DIM + c4 * 4];
    ushort4 u;
    u.x = f2bf(v.x); u.y = f2bf(v.y); u.z = f2bf(v.z); u.w = f2bf(v.w);
    *(ushort4*)&score16[(size_t)row * DIM + c4 * 4] = u;
}

// ---------------- K2: debias + col_valid --------------------------------------
__global__ void aux_kernel(const int* __restrict__ ids, const float* __restrict__ pop,
                           const int* __restrict__ lmask,
                           float* __restrict__ debias, int* __restrict__ colv)
{
    int k = blockIdx.x * 256 + threadIdx.x;
    if (k >= NCOLS) return;
    int id = ids[k];
    debias[k] = __logf(pop[id]);
    int j = k % L1P;
    colv[k] = (j == SEQL) ? 1 : lmask[(k / L1P) * SEQL + j];
}

// ---------------- K3: reject[i][k] = ids[k] in sample i's list ----------------
__global__ void build_reject(const int* __restrict__ ids, unsigned char* __restrict__ reject)
{
    __shared__ int s_ids[L1P];
    int i = blockIdx.y;
    int tid = threadIdx.x;
    if (tid < L1P) s_ids[tid] = ids[i * L1P + tid];
    __syncthreads();
    int k = blockIdx.x * 256 + tid;
    if (k >= NCOLS) return;
    int myid = ids[k];
    int rej = 0;
    for (int j = 0; j < L1P; ++j) rej |= (myid == s_ids[j]);
    reject[(size_t)i * NCOLS + k] = (unsigned char)rej;
}

// ---------------- K4: WT[c][k] = bf16(W_hh[k][c]) -----------------------------
__global__ void wt_kernel(const float* __restrict__ W, ushort* __restrict__ WT)
{
    int c = blockIdx.x;          // 1536
    int k = threadIdx.x;         // 512
    WT[(size_t)c * DIM + k] = f2bf(W[(size_t)k * D3 + c]);
}

// ---------------- K5: gates_x = A @ W_ih + b_ih  (A = bf16 score rows) --------
__global__ void gates_gemm(const ushort* __restrict__ score16, const float* __restrict__ W_ih,
                           const float* __restrict__ b_ih, float* __restrict__ gates)
{
    __shared__ float As[16][64];
    __shared__ float Bs[16][64];
    int tid = threadIdx.x;
    int n0 = blockIdx.x * 64, r0 = blockIdx.y * 64;
    int tx = tid & 15, ty = tid >> 4;

    int arow = tid >> 2, akc = tid & 3;
    int gr = r0 + arow;
    const ushort* Arow = score16 + (size_t)((gr / SEQL) * L1P + (gr % SEQL)) * DIM;
    int bkk = tid >> 4, bnc = tid & 15;

    float acc[4][4] = {};
    for (int k0 = 0; k0 < DIM; k0 += 16) {
        ushort4 av = *(const ushort4*)&Arow[k0 + akc * 4];
        As[akc * 4 + 0][arow] = bf2f(av.x);
        As[akc * 4 + 1][arow] = bf2f(av.y);
        As[akc * 4 + 2][arow] = bf2f(av.z);
        As[akc * 4 + 3][arow] = bf2f(av.w);
        *(float4*)&Bs[bkk][bnc * 4] =
            *(const float4*)&W_ih[(size_t)(k0 + bkk) * D3 + n0 + bnc * 4];
        __syncthreads();
#pragma unroll
        for (int kk = 0; kk < 16; ++kk) {
            float4 a = *(float4*)&As[kk][ty * 4];
            float4 b = *(float4*)&Bs[kk][tx * 4];
            float aa[4] = {a.x, a.y, a.z, a.w};
            float bb[4] = {b.x, b.y, b.z, b.w};
#pragma unroll
            for (int u = 0; u < 4; ++u)
#pragma unroll
                for (int v = 0; v < 4; ++v)
                    acc[u][v] = fmaf(aa[u], bb[v], acc[u][v]);
        }
        __syncthreads();
    }
    float4 bv = *(const float4*)&b_ih[n0 + tx * 4];
#pragma unroll
    for (int u = 0; u < 4; ++u) {
        int rr = r0 + ty * 4 + u;
        float4 o;
        o.x = acc[u][0] + bv.x; o.y = acc[u][1] + bv.y;
        o.z = acc[u][2] + bv.z; o.w = acc[u][3] + bv.w;
        *(float4*)&gates[(size_t)rr * D3 + n0 + tx * 4] = o;
    }
}

// ---------------- K6: persistent GRU, one block per sample --------------------
#define CV2(u, flo, fhi) { flo = __uint_as_float((u) << 16); fhi = __uint_as_float((u) & 0xffff0000u); }
__global__ __launch_bounds__(512) void gru_persist(
    const ushort* __restrict__ WT, const float* __restrict__ b_hh,
    const float* __restrict__ gates, ushort* __restrict__ prec16)
{
    __shared__ float hs[DIM];
    int i = blockIdx.x;
    int d = threadIdx.x;
    const ushort* wr = WT + (size_t)d * DIM;
    const ushort* wz = WT + (size_t)(DIM + d) * DIM;
    const ushort* wn = WT + (size_t)(2 * DIM + d) * DIM;
    float br = b_hh[d], bz = b_hh[DIM + d], bn = b_hh[2 * DIM + d];
    hs[d] = 0.f;
    __syncthreads();

    for (int t = 0; t < SEQL; ++t) {
        float ar = br, az = bz, an = bn;
#pragma unroll 2
        for (int k = 0; k < DIM; k += 8) {
            float4 ha = *(const float4*)&hs[k];
            float4 hb = *(const float4*)&hs[k + 4];
            uint4 R = *(const uint4*)(wr + k);
            uint4 Z = *(const uint4*)(wz + k);
            uint4 N = *(const uint4*)(wn + k);
            float w0, w1;
            CV2(R.x, w0, w1); ar = fmaf(ha.x, w0, ar); ar = fmaf(ha.y, w1, ar);
            CV2(R.y, w0, w1); ar = fmaf(ha.z, w0, ar); ar = fmaf(ha.w, w1, ar);
            CV2(R.z, w0, w1); ar = fmaf(hb.x, w0, ar); ar = fmaf(hb.y, w1, ar);
            CV2(R.w, w0, w1); ar = fmaf(hb.z, w0, ar); ar = fmaf(hb.w, w1, ar);
            CV2(Z.x, w0, w1); az = fmaf(ha.x, w0, az); az = fmaf(ha.y, w1, az);
            CV2(Z.y, w0, w1); az = fmaf(ha.z, w0, az); az = fmaf(ha.w, w1, az);
            CV2(Z.z, w0, w1); az = fmaf(hb.x, w0, az); az = fmaf(hb.y, w1, az);
            CV2(Z.w, w0, w1); az = fmaf(hb.z, w0, az); az = fmaf(hb.w, w1, az);
            CV2(N.x, w0, w1); an = fmaf(ha.x, w0, an); an = fmaf(ha.y, w1, an);
            CV2(N.y, w0, w1); an = fmaf(ha.z, w0, an); an = fmaf(ha.w, w1, an);
            CV2(N.z, w0, w1); an = fmaf(hb.x, w0, an); an = fmaf(hb.y, w1, an);
            CV2(N.w, w0, w1); an = fmaf(hb.z, w0, an); an = fmaf(hb.w, w1, an);
        }
        const float* gx = gates + (size_t)(i * SEQL + t) * D3;
        float r = sigm(gx[d] + ar);
        float z = sigm(gx[DIM + d] + az);
        float n = ftanh(gx[2 * DIM + d] + r * an);
        __syncthreads();                        // all reads of hs done
        float hnew = (1.f - z) * n + z * hs[d];
        hs[d] = hnew;
        prec16[(size_t)(i * SEQL + t) * DIM + d] = f2bf(hnew);
        __syncthreads();                        // writes visible before next reads
    }
}

// ---------------- K7: MFMA logits + fixed-ref softmax partial sums ------------
// grid 256: i = blk>>2 (sample), cs = blk&3 (column quarter, 1616 cols each).
// Block 256 thr = 4 waves; wave w owns row tiles {2w, 2w+1} (tile 7 skipped;
// tile 6 rows 100..111 are invalid -> every j must be guarded by j < SEQL).
__global__ __launch_bounds__(256, 1) void logits_mfma(
    const ushort* __restrict__ prec16, const ushort* __restrict__ score16,
    const float* __restrict__ debias, const int* __restrict__ colv,
    const unsigned char* __restrict__ reject,
    float* __restrict__ s_glob, float* __restrict__ label_glob)
{
    int i  = blockIdx.x >> 2;
    int cs = blockIdx.x & 3;
    int lane = threadIdx.x & 63;
    int w    = threadIdx.x >> 6;
    int l15  = lane & 15, quad = lane >> 4;

    // preload A fragments: rows i*100 + tile*16 + l15, K chunks of 32
    bf16x8 afrag[2][16];
    bool live1 = (w < 3);                       // tile 7 (w==3,u==1) skipped
    {
        int r0 = i * SEQL + (2 * w) * 16 + l15;
        const ushort* ap = prec16 + (size_t)r0 * DIM + quad * 8;
#pragma unroll
        for (int c = 0; c < 16; ++c) afrag[0][c] = *(const bf16x8*)(ap + c * 32);
    }
    if (live1) {
        int r1 = i * SEQL + (2 * w + 1) * 16 + l15;
        const ushort* ap = prec16 + (size_t)r1 * DIM + quad * 8;
#pragma unroll
        for (int c = 0; c < 16; ++c) afrag[1][c] = *(const bf16x8*)(ap + c * 32);
    }

    const unsigned char* rej = reject + (size_t)i * NCOLS;
    float srun0[4] = {0.f, 0.f, 0.f, 0.f};
    float srun1[4] = {0.f, 0.f, 0.f, 0.f};
    int n_base = cs * 1616;

    for (int st = 0; st < 101; ++st) {
        int n = n_base + st * 16 + l15;
        const ushort* bp = score16 + (size_t)n * DIM + quad * 8;
        f32x4 acc0 = {0.f, 0.f, 0.f, 0.f};
        f32x4 acc1 = {0.f, 0.f, 0.f, 0.f};
#pragma unroll
        for (int c = 0; c < 16; ++c) {
            bf16x8 b = *(const bf16x8*)(bp + c * 32);
            acc0 = __builtin_amdgcn_mfma_f32_16x16x32_bf16(afrag[0][c], b, acc0, 0, 0, 0);
            if (live1)
                acc1 = __builtin_amdgcn_mfma_f32_16x16x32_bf16(afrag[1][c], b, acc1, 0, 0, 0);
        }
        float db = debias[n];
        int   cv = colv[n];
        int   rj = rej[n];
        int   jj = n - i * L1P - 1;             // row whose target is column n
        {
            int rowb = (2 * w) * 16 + quad * 4;
#pragma unroll
            for (int p = 0; p < 4; ++p) {
                int j = rowb + p;
                float l = acc0[p] - db;
                bool is_t = (j == jj);
                bool msk = (cv == 0) || (rj && !is_t);
                l = msk ? MASKV : l;
                if (is_t && j < SEQL) label_glob[i * SEQL + j] = l;
                if (j < SEQL) srun0[p] += __expf(l - M0);
            }
        }
        if (live1) {
            int rowb = (2 * w + 1) * 16 + quad * 4;
#pragma unroll
            for (int p = 0; p < 4; ++p) {
                int j = rowb + p;
                float l = acc1[p] - db;
                bool is_t = (j == jj);
                bool msk = (cv == 0) || (rj && !is_t);
                l = msk ? MASKV : l;
                if (is_t && j < SEQL) label_glob[i * SEQL + j] = l;
                if (j < SEQL) srun1[p] += __expf(l - M0);
            }
        }
    }
    // reduce partial sums over the 16 lanes sharing a row, then atomic merge
#pragma unroll
    for (int p = 0; p < 4; ++p) {
        float s = srun0[p];
        s += __shfl_xor(s, 1); s += __shfl_xor(s, 2);
        s += __shfl_xor(s, 4); s += __shfl_xor(s, 8);
        if (l15 == 0) {
            int j = (2 * w) * 16 + quad * 4 + p;
            if (j < SEQL) atomicAdd(&s_glob[i * SEQL + j], s);
        }
    }
    if (live1) {
#pragma unroll
        for (int p = 0; p < 4; ++p) {
            float s = srun1[p];
            s += __shfl_xor(s, 1); s += __shfl_xor(s, 2);
            s += __shfl_xor(s, 4); s += __shfl_xor(s, 8);
            if (l15 == 0) {
                int j = (2 * w + 1) * 16 + quad * 4 + p;
                if (j < SEQL) atomicAdd(&s_glob[i * SEQL + j], s);
            }
        }
    }
}

// ---------------- K8: per-row NLL + weighted sum ------------------------------
__global__ void nll_reduce(const float* __restrict__ s_glob, const float* __restrict__ label_glob,
                           const int* __restrict__ lmask, float* __restrict__ acc)
{
    int r = blockIdx.x * 256 + threadIdx.x;
    float v = 0.f, wt = 0.f;
    if (r < NROWS) {
        wt = (lmask[r] != 0) ? 1.f : 0.f;
        v  = (M0 + __logf(s_glob[r]) - label_glob[r]) * wt;
    }
#pragma unroll
    for (int o = 32; o; o >>= 1) { v += __shfl_down(v, o); wt += __shfl_down(wt, o); }
    if ((threadIdx.x & 63) == 0) { atomicAdd(&acc[0], v); atomicAdd(&acc[1], wt); }
}

// ---------------- K9: finalize ------------------------------------------------
__global__ void finalize(const float* __restrict__ acc, float* __restrict__ out)
{
    out[0] = acc[0] / fmaxf(acc[1], 1.f);
}

extern "C" void kernel_launch(void* const* d_in, const int* in_sizes, int n_in,
                              void* d_out, int out_size, void* d_ws, size_t ws_size,
                              hipStream_t stream)
{
    const int*   ids   = (const int*)d_in[0];
    const int*   lmask = (const int*)d_in[1];
    const float* pop   = (const float*)d_in[2];
    const float* emb   = (const float*)d_in[3];
    const float* W_ih  = (const float*)d_in[4];
    const float* W_hh  = (const float*)d_in[5];
    const float* b_ih  = (const float*)d_in[6];
    const float* b_hh  = (const float*)d_in[7];
    float* out = (float*)d_out;

    // workspace layout (~55 MB)
    ushort* score16 = (ushort*)d_ws;                               // 6464*512 bf16
    ushort* prec16  = score16 + (size_t)NCOLS * DIM;               // 6416*512 bf16 (incl pad)
    ushort* WT      = prec16 + (size_t)(NROWS + 16) * DIM;         // 1536*512 bf16
    float*  debias  = (float*)(WT + (size_t)D3 * DIM);             // 6464 f32
    int*    colv    = (int*)(debias + NCOLS);                      // 6464 i32
    unsigned char* rej = (unsigned char*)(colv + NCOLS);           // 64*6464 u8
    float*  gates   = (float*)(rej + (size_t)BSZ * NCOLS + 64);    // 6400*1536 f32 (offset keeps 16B align)
    float*  s_glob  = gates + (size_t)NROWS * D3;                  // 6400 f32
    float*  label_g = s_glob + NROWS;                              // 6400 f32
    float*  acc     = label_g + NROWS;                             // 2 f32

    init_ws<<<25, 256, 0, stream>>>(s_glob, acc, (unsigned*)(prec16 + (size_t)NROWS * DIM));
    gather_embs<<<(NCOLS * 128) / 256, 256, 0, stream>>>(ids, emb, score16);
    aux_kernel<<<(NCOLS + 255) / 256, 256, 0, stream>>>(ids, pop, lmask, debias, colv);
    build_reject<<<dim3((NCOLS + 255) / 256, BSZ), 256, 0, stream>>>(ids, rej);
    wt_kernel<<<D3, DIM, 0, stream>>>(W_hh, WT);
    gates_gemm<<<dim3(D3 / 64, NROWS / 64), 256, 0, stream>>>(score16, W_ih, b_ih, gates);
    gru_persist<<<BSZ, DIM, 0, stream>>>(WT, b_hh, gates, prec16);
    logits_mfma<<<BSZ * 4, 256, 0, stream>>>(prec16, score16, debias, colv, rej, s_glob, label_g);
    nll_reduce<<<(NROWS + 255) / 256, 256, 0, stream>>>(s_glob, label_g, lmask, acc);
    finalize<<<1, 1, 0, stream>>>(acc, out);
}

// Round 4
// 1708.886 us; speedup vs baseline: 8.2746x; 2.9390x over previous
//
#include <hip/hip_runtime.h>
#include <hip/hip_bf16.h>

#define BSZ   64
#define SEQL  100
#define DIM   512
#define L1P   101
#define NCOLS 6464     // BSZ*L1P
#define NROWS 6400     // BSZ*SEQL
#define D3    1536
#define MASKV -10000.0f
#define M0    16.0f    // fixed softmax reference: logits provably < ~10
#define GRU_NB 32      // persistent GRU blocks (must all be co-resident; 32 << 256 CUs)

typedef __attribute__((ext_vector_type(8))) short bf16x8;
typedef __attribute__((ext_vector_type(4))) float f32x4;

__device__ __forceinline__ float sigm(float x)  { return 1.f / (1.f + __expf(-x)); }
__device__ __forceinline__ float ftanh(float x) { float e = __expf(2.f * x); return 1.f - 2.f / (e + 1.f); }
__device__ __forceinline__ ushort f2bf(float x) {
    __hip_bfloat16 b = __float2bfloat16(x);
    return *(ushort*)&b;
}

// ---------------- K0: init workspace ------------------------------------------
__global__ void init_ws(float* s_glob, float* acc, unsigned* prec_pad, unsigned* ctr)
{
    int t = blockIdx.x * 256 + threadIdx.x;     // 6400 threads
    if (t < NROWS) s_glob[t] = 0.f;
    if (t < 2) acc[t] = 0.f;
    if (t < 4096) prec_pad[t] = 0;              // rows 6400..6415 of prec16
    if (t == 0) ctr[0] = 0u;                    // GRU barrier counter
}

// ---------------- K1: gather score16[k][:] = bf16(id_emb[ids[k]][:]) ----------
__global__ void gather_embs(const int* __restrict__ ids, const float* __restrict__ emb,
                            ushort* __restrict__ score16)
{
    int idx = blockIdx.x * 256 + threadIdx.x;   // 6464*128
    int row = idx >> 7, c4 = idx & 127;
    int id = ids[row];
    float4 v = *(const float4*)&emb[(size_t)id * DIM + c4 * 4];
    ushort4 u;
    u.x = f2bf(v.x); u.y = f2bf(v.y); u.z = f2bf(v.z); u.w = f2bf(v.w);
    *(ushort4*)&score16[(size_t)row * DIM + c4 * 4] = u;
}

// ---------------- K2: debias + col_valid --------------------------------------
__global__ void aux_kernel(const int* __restrict__ ids, const float* __restrict__ pop,
                           const int* __restrict__ lmask,
                           float* __restrict__ debias, int* __restrict__ colv)
{
    int k = blockIdx.x * 256 + threadIdx.x;
    if (k >= NCOLS) return;
    int id = ids[k];
    debias[k] = __logf(pop[id]);
    int j = k % L1P;
    colv[k] = (j == SEQL) ? 1 : lmask[(k / L1P) * SEQL + j];
}

// ---------------- K3: reject[i][k] = ids[k] in sample i's list ----------------
__global__ void build_reject(const int* __restrict__ ids, unsigned char* __restrict__ reject)
{
    __shared__ int s_ids[L1P];
    int i = blockIdx.y;
    int tid = threadIdx.x;
    if (tid < L1P) s_ids[tid] = ids[i * L1P + tid];
    __syncthreads();
    int k = blockIdx.x * 256 + tid;
    if (k >= NCOLS) return;
    int myid = ids[k];
    int rej = 0;
    for (int j = 0; j < L1P; ++j) rej |= (myid == s_ids[j]);
    reject[(size_t)i * NCOLS + k] = (unsigned char)rej;
}

// ---------------- K4: WT[c][k] = bf16(W[k][c])  (512x1536 -> 1536x512) --------
__global__ void wt_kernel(const float* __restrict__ W, ushort* __restrict__ WT)
{
    int c = blockIdx.x;          // 1536
    int k = threadIdx.x;         // 512
    WT[(size_t)c * DIM + k] = f2bf(W[(size_t)k * D3 + c]);
}

// ---------------- K5: gates_x = x @ W_ih + b_ih  via MFMA ---------------------
// grid (24,100): 64-col x 64-row C tile. 4 waves; wave w = M-tile w, 4 N-tiles.
__global__ __launch_bounds__(256) void gates_mfma(
    const ushort* __restrict__ score16, const ushort* __restrict__ WIT,
    const float* __restrict__ b_ih, float* __restrict__ gates)
{
    int n0 = blockIdx.x * 64, r0 = blockIdx.y * 64;
    int tid = threadIdx.x;
    int w = tid >> 6, lane = tid & 63, l15 = lane & 15, quad = lane >> 4;
    int r = r0 + w * 16 + l15;                  // gates row = sample*100 + step
    int i = r / SEQL, j = r % SEQL;
    const ushort* ap = score16 + (size_t)(i * L1P + j) * DIM + quad * 8;
    bf16x8 af[16];
#pragma unroll
    for (int c = 0; c < 16; ++c) af[c] = *(const bf16x8*)(ap + c * 32);

    f32x4 acc[4] = {{0,0,0,0},{0,0,0,0},{0,0,0,0},{0,0,0,0}};
#pragma unroll
    for (int c = 0; c < 16; ++c) {
#pragma unroll
        for (int nt = 0; nt < 4; ++nt) {
            const ushort* bp = WIT + (size_t)(n0 + nt * 16 + l15) * DIM + quad * 8 + c * 32;
            bf16x8 bb = *(const bf16x8*)bp;
            acc[nt] = __builtin_amdgcn_mfma_f32_16x16x32_bf16(af[c], bb, acc[nt], 0, 0, 0);
        }
    }
#pragma unroll
    for (int nt = 0; nt < 4; ++nt) {
        int n = n0 + nt * 16 + l15;
        float bi = b_ih[n];
#pragma unroll
        for (int p = 0; p < 4; ++p) {
            int rr = r0 + w * 16 + quad * 4 + p;
            gates[(size_t)rr * D3 + n] = acc[nt][p] + bi;
        }
    }
}

// ---------------- K6: batch-wide persistent MFMA GRU --------------------------
// 32 blocks x 256 thr. Block b owns dims [b*16, b*16+16): W-slab (48 cols x 512)
// lives in LDS for all 100 steps. Wave w owns samples [w*16, w*16+16).
// Cross-block h exchange via prec16 (bf16) + device-scope barrier each step.
__global__ __launch_bounds__(256) void gru_mfma(
    const ushort* __restrict__ WT,      // [1536][512] bf16 = W_hh^T
    const float* __restrict__ b_hh,
    const float* __restrict__ gates,    // [6400][1536] f32 (includes b_ih)
    ushort* __restrict__ prec16,        // [(6400+16)][512] bf16 per-step h
    unsigned* __restrict__ ctr)
{
    __shared__ ushort Wslab[48][520];   // +8 pad: lanes map to distinct bank groups
    __shared__ float  hsl[64][17];      // f32 h_prev for this block's 16 dims (+1 pad)
    int b = blockIdx.x;
    int tid = threadIdx.x;
    int w = tid >> 6, lane = tid & 63, l15 = lane & 15, quad = lane >> 4;

    // stage W slab once: row g*16+c  <-  WT row (g*512 + b*16 + c)
    for (int row = w; row < 48; row += 4) {
        int g = row >> 4, c = row & 15;
        const ushort* src = WT + (size_t)(g * 512 + b * 16 + c) * DIM;
        *(bf16x8*)&Wslab[row][lane * 8] = *(const bf16x8*)(src + lane * 8);
    }
    for (int idx = tid; idx < 64 * 16; idx += 256) hsl[idx >> 4][idx & 15] = 0.f;
    __syncthreads();

    int d = b * 16 + l15;               // this thread's global dim
    float bhr = b_hh[d], bhz = b_hh[512 + d], bhn = b_hh[1024 + d];

    for (int t = 0; t < SEQL; ++t) {
        f32x4 acc[3] = {{0,0,0,0},{0,0,0,0},{0,0,0,0}};
        if (t > 0) {
            // A-frags: h(t-1) rows for samples w*16 + l15
            const ushort* ap = prec16 + ((size_t)(w * 16 + l15) * SEQL + (t - 1)) * DIM + quad * 8;
            bf16x8 af[16];
#pragma unroll
            for (int c = 0; c < 16; ++c) af[c] = *(const bf16x8*)(ap + c * 32);
#pragma unroll
            for (int c = 0; c < 16; ++c) {
#pragma unroll
                for (int g = 0; g < 3; ++g) {
                    bf16x8 bb = *(const bf16x8*)&Wslab[g * 16 + l15][c * 32 + quad * 8];
                    acc[g] = __builtin_amdgcn_mfma_f32_16x16x32_bf16(af[c], bb, acc[g], 0, 0, 0);
                }
            }
        }
        // epilogue: 4 samples per thread (C layout: col=l15=dim, row=quad*4+p=sample)
#pragma unroll
        for (int p = 0; p < 4; ++p) {
            int ss = w * 16 + quad * 4 + p;
            const float* gx = gates + ((size_t)ss * SEQL + t) * D3;
            float xr = gx[d], xz = gx[512 + d], xn = gx[1024 + d];
            float r = sigm(xr + acc[0][p] + bhr);
            float z = sigm(xz + acc[1][p] + bhz);
            float hn = acc[2][p] + bhn;
            float n = ftanh(xn + r * hn);
            float hp = hsl[ss][l15];
            float hnew = (1.f - z) * n + z * hp;
            hsl[ss][l15] = hnew;
            prec16[((size_t)ss * SEQL + t) * DIM + d] = f2bf(hnew);
        }
        // device-scope barrier: release stores, arrive, spin, acquire
        __threadfence();
        __syncthreads();
        if (tid == 0) {
            atomicAdd(ctr, 1u);
            unsigned target = (unsigned)(GRU_NB * (t + 1));
            while (atomicAdd(ctr, 0u) < target) __builtin_amdgcn_s_sleep(1);
        }
        __syncthreads();
        __threadfence();
    }
}

// ---------------- K7: MFMA logits + fixed-ref softmax partial sums ------------
__global__ __launch_bounds__(256, 1) void logits_mfma(
    const ushort* __restrict__ prec16, const ushort* __restrict__ score16,
    const float* __restrict__ debias, const int* __restrict__ colv,
    const unsigned char* __restrict__ reject,
    float* __restrict__ s_glob, float* __restrict__ label_glob)
{
    int i  = blockIdx.x >> 2;
    int cs = blockIdx.x & 3;
    int lane = threadIdx.x & 63;
    int w    = threadIdx.x >> 6;
    int l15  = lane & 15, quad = lane >> 4;

    bf16x8 afrag[2][16];
    bool live1 = (w < 3);                       // tile 7 skipped
    {
        int r0 = i * SEQL + (2 * w) * 16 + l15;
        const ushort* ap = prec16 + (size_t)r0 * DIM + quad * 8;
#pragma unroll
        for (int c = 0; c < 16; ++c) afrag[0][c] = *(const bf16x8*)(ap + c * 32);
    }
    if (live1) {
        int r1 = i * SEQL + (2 * w + 1) * 16 + l15;
        const ushort* ap = prec16 + (size_t)r1 * DIM + quad * 8;
#pragma unroll
        for (int c = 0; c < 16; ++c) afrag[1][c] = *(const bf16x8*)(ap + c * 32);
    }

    const unsigned char* rej = reject + (size_t)i * NCOLS;
    float srun0[4] = {0.f, 0.f, 0.f, 0.f};
    float srun1[4] = {0.f, 0.f, 0.f, 0.f};
    int n_base = cs * 1616;

    for (int st = 0; st < 101; ++st) {
        int n = n_base + st * 16 + l15;
        const ushort* bp = score16 + (size_t)n * DIM + quad * 8;
        f32x4 acc0 = {0.f, 0.f, 0.f, 0.f};
        f32x4 acc1 = {0.f, 0.f, 0.f, 0.f};
#pragma unroll
        for (int c = 0; c < 16; ++c) {
            bf16x8 b = *(const bf16x8*)(bp + c * 32);
            acc0 = __builtin_amdgcn_mfma_f32_16x16x32_bf16(afrag[0][c], b, acc0, 0, 0, 0);
            if (live1)
                acc1 = __builtin_amdgcn_mfma_f32_16x16x32_bf16(afrag[1][c], b, acc1, 0, 0, 0);
        }
        float db = debias[n];
        int   cv = colv[n];
        int   rj = rej[n];
        int   jj = n - i * L1P - 1;
        {
            int rowb = (2 * w) * 16 + quad * 4;
#pragma unroll
            for (int p = 0; p < 4; ++p) {
                int j = rowb + p;
                float l = acc0[p] - db;
                bool is_t = (j == jj);
                bool msk = (cv == 0) || (rj && !is_t);
                l = msk ? MASKV : l;
                if (is_t && j < SEQL) label_glob[i * SEQL + j] = l;
                if (j < SEQL) srun0[p] += __expf(l - M0);
            }
        }
        if (live1) {
            int rowb = (2 * w + 1) * 16 + quad * 4;
#pragma unroll
            for (int p = 0; p < 4; ++p) {
                int j = rowb + p;
                float l = acc1[p] - db;
                bool is_t = (j == jj);
                bool msk = (cv == 0) || (rj && !is_t);
                l = msk ? MASKV : l;
                if (is_t && j < SEQL) label_glob[i * SEQL + j] = l;
                if (j < SEQL) srun1[p] += __expf(l - M0);
            }
        }
    }
#pragma unroll
    for (int p = 0; p < 4; ++p) {
        float s = srun0[p];
        s += __shfl_xor(s, 1); s += __shfl_xor(s, 2);
        s += __shfl_xor(s, 4); s += __shfl_xor(s, 8);
        if (l15 == 0) {
            int j = (2 * w) * 16 + quad * 4 + p;
            if (j < SEQL) atomicAdd(&s_glob[i * SEQL + j], s);
        }
    }
    if (live1) {
#pragma unroll
        for (int p = 0; p < 4; ++p) {
            float s = srun1[p];
            s += __shfl_xor(s, 1); s += __shfl_xor(s, 2);
            s += __shfl_xor(s, 4); s += __shfl_xor(s, 8);
            if (l15 == 0) {
                int j = (2 * w + 1) * 16 + quad * 4 + p;
                if (j < SEQL) atomicAdd(&s_glob[i * SEQL + j], s);
            }
        }
    }
}

// ---------------- K8: per-row NLL + weighted sum ------------------------------
__global__ void nll_reduce(const float* __restrict__ s_glob, const float* __restrict__ label_glob,
                           const int* __restrict__ lmask, float* __restrict__ acc)
{
    int r = blockIdx.x * 256 + threadIdx.x;
    float v = 0.f, wt = 0.f;
    if (r < NROWS) {
        wt = (lmask[r] != 0) ? 1.f : 0.f;
        v  = (M0 + __logf(s_glob[r]) - label_glob[r]) * wt;
    }
#pragma unroll
    for (int o = 32; o; o >>= 1) { v += __shfl_down(v, o); wt += __shfl_down(wt, o); }
    if ((threadIdx.x & 63) == 0) { atomicAdd(&acc[0], v); atomicAdd(&acc[1], wt); }
}

// ---------------- K9: finalize ------------------------------------------------
__global__ void finalize(const float* __restrict__ acc, float* __restrict__ out)
{
    out[0] = acc[0] / fmaxf(acc[1], 1.f);
}

extern "C" void kernel_launch(void* const* d_in, const int* in_sizes, int n_in,
                              void* d_out, int out_size, void* d_ws, size_t ws_size,
                              hipStream_t stream)
{
    const int*   ids   = (const int*)d_in[0];
    const int*   lmask = (const int*)d_in[1];
    const float* pop   = (const float*)d_in[2];
    const float* emb   = (const float*)d_in[3];
    const float* W_ih  = (const float*)d_in[4];
    const float* W_hh  = (const float*)d_in[5];
    const float* b_ih  = (const float*)d_in[6];
    const float* b_hh  = (const float*)d_in[7];
    float* out = (float*)d_out;

    // workspace layout (~57 MB)
    ushort* score16 = (ushort*)d_ws;                               // 6464*512 bf16
    ushort* prec16  = score16 + (size_t)NCOLS * DIM;               // 6416*512 bf16 (incl pad)
    ushort* WT      = prec16 + (size_t)(NROWS + 16) * DIM;         // 1536*512 bf16 (W_hh^T)
    ushort* WIT     = WT + (size_t)D3 * DIM;                       // 1536*512 bf16 (W_ih^T)
    float*  debias  = (float*)(WIT + (size_t)D3 * DIM);            // 6464 f32
    int*    colv    = (int*)(debias + NCOLS);                      // 6464 i32
    unsigned char* rej = (unsigned char*)(colv + NCOLS);           // 64*6464 u8
    float*  gates   = (float*)(rej + (size_t)BSZ * NCOLS + 64);    // 6400*1536 f32
    float*  s_glob  = gates + (size_t)NROWS * D3;                  // 6400 f32
    float*  label_g = s_glob + NROWS;                              // 6400 f32
    float*  acc     = label_g + NROWS;                             // 2 f32
    unsigned* ctr   = (unsigned*)(acc + 2);                        // 1 u32 barrier ctr

    init_ws<<<25, 256, 0, stream>>>(s_glob, acc, (unsigned*)(prec16 + (size_t)NROWS * DIM), ctr);
    gather_embs<<<(NCOLS * 128) / 256, 256, 0, stream>>>(ids, emb, score16);
    aux_kernel<<<(NCOLS + 255) / 256, 256, 0, stream>>>(ids, pop, lmask, debias, colv);
    build_reject<<<dim3((NCOLS + 255) / 256, BSZ), 256, 0, stream>>>(ids, rej);
    wt_kernel<<<D3, DIM, 0, stream>>>(W_hh, WT);
    wt_kernel<<<D3, DIM, 0, stream>>>(W_ih, WIT);
    gates_mfma<<<dim3(24, 100), 256, 0, stream>>>(score16, WIT, b_ih, gates);
    gru_mfma<<<GRU_NB, 256, 0, stream>>>(WT, b_hh, gates, prec16, ctr);
    logits_mfma<<<BSZ * 4, 256, 0, stream>>>(prec16, score16, debias, colv, rej, s_glob, label_g);
    nll_reduce<<<(NROWS + 255) / 256, 256, 0, stream>>>(s_glob, label_g, lmask, acc);
    finalize<<<1, 1, 0, stream>>>(acc, out);
}

// Round 5
// 1442.159 us; speedup vs baseline: 9.8049x; 1.1850x over previous
//
#include <hip/hip_runtime.h>
#include <hip/hip_bf16.h>

#define BSZ   64
#define SEQL  100
#define DIM   512
#define L1P   101
#define NCOLS 6464     // BSZ*L1P
#define NROWS 6400     // BSZ*SEQL
#define D3    1536
#define MASKV -10000.0f
#define M0    16.0f    // fixed softmax reference: logits provably < ~10
#define GRU_NB 32      // persistent GRU blocks (32 << 256 CUs -> co-resident)

typedef __attribute__((ext_vector_type(8))) short bf16x8;
typedef __attribute__((ext_vector_type(4))) float f32x4;

__device__ __forceinline__ float sigm(float x)  { return 1.f / (1.f + __expf(-x)); }
__device__ __forceinline__ float ftanh(float x) { float e = __expf(2.f * x); return 1.f - 2.f / (e + 1.f); }
__device__ __forceinline__ ushort f2bf(float x) {
    __hip_bfloat16 b = __float2bfloat16(x);
    return *(ushort*)&b;
}

// ---------------- K0: init workspace ------------------------------------------
__global__ void init_ws(float* s_glob, float* acc, unsigned* prec_pad, unsigned* flags)
{
    int t = blockIdx.x * 256 + threadIdx.x;     // 6400 threads
    if (t < NROWS) s_glob[t] = 0.f;
    if (t < 2) acc[t] = 0.f;
    if (t < 4096) prec_pad[t] = 0;              // rows 6400..6415 of prec16
    if (t < GRU_NB) flags[t] = 0u;              // GRU barrier flags
}

// ---------------- K1: gather score16[k][:] = bf16(id_emb[ids[k]][:]) ----------
__global__ void gather_embs(const int* __restrict__ ids, const float* __restrict__ emb,
                            ushort* __restrict__ score16)
{
    int idx = blockIdx.x * 256 + threadIdx.x;   // 6464*128
    int row = idx >> 7, c4 = idx & 127;
    int id = ids[row];
    float4 v = *(const float4*)&emb[(size_t)id * DIM + c4 * 4];
    ushort4 u;
    u.x = f2bf(v.x); u.y = f2bf(v.y); u.z = f2bf(v.z); u.w = f2bf(v.w);
    *(ushort4*)&score16[(size_t)row * DIM + c4 * 4] = u;
}

// ---------------- K2: debias + col_valid --------------------------------------
__global__ void aux_kernel(const int* __restrict__ ids, const float* __restrict__ pop,
                           const int* __restrict__ lmask,
                           float* __restrict__ debias, int* __restrict__ colv)
{
    int k = blockIdx.x * 256 + threadIdx.x;
    if (k >= NCOLS) return;
    int id = ids[k];
    debias[k] = __logf(pop[id]);
    int j = k % L1P;
    colv[k] = (j == SEQL) ? 1 : lmask[(k / L1P) * SEQL + j];
}

// ---------------- K3: reject[i][k] = ids[k] in sample i's list ----------------
__global__ void build_reject(const int* __restrict__ ids, unsigned char* __restrict__ reject)
{
    __shared__ int s_ids[L1P];
    int i = blockIdx.y;
    int tid = threadIdx.x;
    if (tid < L1P) s_ids[tid] = ids[i * L1P + tid];
    __syncthreads();
    int k = blockIdx.x * 256 + tid;
    if (k >= NCOLS) return;
    int myid = ids[k];
    int rej = 0;
    for (int j = 0; j < L1P; ++j) rej |= (myid == s_ids[j]);
    reject[(size_t)i * NCOLS + k] = (unsigned char)rej;
}

// ---------------- K4: WT[c][k] = bf16(W[k][c])  (512x1536 -> 1536x512) --------
__global__ void wt_kernel(const float* __restrict__ W, ushort* __restrict__ WT)
{
    int c = blockIdx.x;          // 1536
    int k = threadIdx.x;         // 512
    WT[(size_t)c * DIM + k] = f2bf(W[(size_t)k * D3 + c]);
}

// ---------------- K5: gates_x = x @ W_ih + b_ih  via MFMA ---------------------
__global__ __launch_bounds__(256) void gates_mfma(
    const ushort* __restrict__ score16, const ushort* __restrict__ WIT,
    const float* __restrict__ b_ih, float* __restrict__ gates)
{
    int n0 = blockIdx.x * 64, r0 = blockIdx.y * 64;
    int tid = threadIdx.x;
    int w = tid >> 6, lane = tid & 63, l15 = lane & 15, quad = lane >> 4;
    int r = r0 + w * 16 + l15;                  // gates row = sample*100 + step
    int i = r / SEQL, j = r % SEQL;
    const ushort* ap = score16 + (size_t)(i * L1P + j) * DIM + quad * 8;
    bf16x8 af[16];
#pragma unroll
    for (int c = 0; c < 16; ++c) af[c] = *(const bf16x8*)(ap + c * 32);

    f32x4 acc[4] = {{0,0,0,0},{0,0,0,0},{0,0,0,0},{0,0,0,0}};
#pragma unroll
    for (int c = 0; c < 16; ++c) {
#pragma unroll
        for (int nt = 0; nt < 4; ++nt) {
            const ushort* bp = WIT + (size_t)(n0 + nt * 16 + l15) * DIM + quad * 8 + c * 32;
            bf16x8 bb = *(const bf16x8*)bp;
            acc[nt] = __builtin_amdgcn_mfma_f32_16x16x32_bf16(af[c], bb, acc[nt], 0, 0, 0);
        }
    }
#pragma unroll
    for (int nt = 0; nt < 4; ++nt) {
        int n = n0 + nt * 16 + l15;
        float bi = b_ih[n];
#pragma unroll
        for (int p = 0; p < 4; ++p) {
            int rr = r0 + w * 16 + quad * 4 + p;
            gates[(size_t)rr * D3 + n] = acc[nt][p] + bi;
        }
    }
}

// ---------------- K6: batch-wide persistent MFMA GRU --------------------------
// 32 blocks x 256 thr. Block b owns dims [b*16, b*16+16): W-slab (48 x 512) in
// LDS for all 100 steps. Cross-block h exchange is fence-free: h published to
// double-buffered hx via agent-scope relaxed atomic stores (bypass non-coherent
// L2, land at LLC; vmcnt drained by __syncthreads), flags[b]=t+1 release-store,
// readers spin on acquire loads of the 32 flags then agent-load h(t-1).
// Protocol safety: computing step t requires all flags >= t, so every reader of
// h(t-1) has finished before anyone can write slot (t+1)&1 != (t-1)&1.
__global__ __launch_bounds__(256) void gru_mfma(
    const ushort* __restrict__ WT,      // [1536][512] bf16 = W_hh^T
    const float* __restrict__ b_hh,
    const float* __restrict__ gates,    // [6400][1536] f32 (includes b_ih)
    ushort* __restrict__ prec16,        // [(6400+16)][512] bf16 per-step h
    unsigned long long* __restrict__ hx,// [2][64][128] ulong = bf16 h exchange
    unsigned* __restrict__ flags)       // [32]
{
    __shared__ ushort Wslab[48][520];
    __shared__ float  hsl[64][17];      // f32 h for this block's 16 dims
    int b = blockIdx.x;
    int tid = threadIdx.x;
    int w = tid >> 6, lane = tid & 63, l15 = lane & 15, quad = lane >> 4;

    for (int row = w; row < 48; row += 4) {
        int g = row >> 4, c = row & 15;
        const ushort* src = WT + (size_t)(g * 512 + b * 16 + c) * DIM;
        *(bf16x8*)&Wslab[row][lane * 8] = *(const bf16x8*)(src + lane * 8);
    }
    for (int idx = tid; idx < 64 * 16; idx += 256) hsl[idx >> 4][idx & 15] = 0.f;
    __syncthreads();

    int d = b * 16 + l15;               // this thread's global dim
    float bhr = b_hh[d], bhz = b_hh[512 + d], bhn = b_hh[1024 + d];
    int s_s = tid >> 2, s_p = tid & 3;  // publish phase: sample, 4-dim group

    for (int t = 0; t < SEQL; ++t) {
        // prefetch gates for step t (independent of h) - in flight during spin
        float xr[4], xz[4], xn[4];
#pragma unroll
        for (int p = 0; p < 4; ++p) {
            int ss = w * 16 + quad * 4 + p;
            const float* gx = gates + ((size_t)ss * SEQL + t) * D3;
            xr[p] = gx[d]; xz[p] = gx[512 + d]; xn[p] = gx[1024 + d];
        }
        f32x4 acc[3] = {{0,0,0,0},{0,0,0,0},{0,0,0,0}};
        if (t > 0) {
            if (tid < GRU_NB) {
                unsigned tgt = (unsigned)t;
                while (__hip_atomic_load(&flags[tid], __ATOMIC_ACQUIRE,
                                         __HIP_MEMORY_SCOPE_AGENT) < tgt)
                    __builtin_amdgcn_s_sleep(1);
            }
            __syncthreads();
            int sm = w * 16 + l15;
            const unsigned long long* hp =
                hx + ((size_t)((t - 1) & 1) * 64 + sm) * 128 + quad * 2;
            bf16x8 af[16];
#pragma unroll
            for (int c = 0; c < 16; ++c) {
                unsigned long long lo = __hip_atomic_load(hp + c * 8 + 0, __ATOMIC_RELAXED,
                                                          __HIP_MEMORY_SCOPE_AGENT);
                unsigned long long hi = __hip_atomic_load(hp + c * 8 + 1, __ATOMIC_RELAXED,
                                                          __HIP_MEMORY_SCOPE_AGENT);
                union { unsigned long long q[2]; bf16x8 v; } u;
                u.q[0] = lo; u.q[1] = hi;
                af[c] = u.v;
            }
#pragma unroll
            for (int c = 0; c < 16; ++c) {
#pragma unroll
                for (int g = 0; g < 3; ++g) {
                    bf16x8 bb = *(const bf16x8*)&Wslab[g * 16 + l15][c * 32 + quad * 8];
                    acc[g] = __builtin_amdgcn_mfma_f32_16x16x32_bf16(af[c], bb, acc[g], 0, 0, 0);
                }
            }
        }
        // epilogue: 4 samples/thread (C layout: col=l15=dim, row=quad*4+p=sample)
#pragma unroll
        for (int p = 0; p < 4; ++p) {
            int ss = w * 16 + quad * 4 + p;
            float r = sigm(xr[p] + acc[0][p] + bhr);
            float z = sigm(xz[p] + acc[1][p] + bhz);
            float n = ftanh(xn[p] + r * (acc[2][p] + bhn));
            float hnew = (1.f - z) * n + z * hsl[ss][l15];
            hsl[ss][l15] = hnew;
            __builtin_nontemporal_store(f2bf(hnew),
                &prec16[((size_t)ss * SEQL + t) * DIM + d]);   // keeps L2 clean
        }
        __syncthreads();                // hsl writes visible to publish phase
        {
            float f0 = hsl[s_s][s_p * 4 + 0], f1 = hsl[s_s][s_p * 4 + 1];
            float f2 = hsl[s_s][s_p * 4 + 2], f3 = hsl[s_s][s_p * 4 + 3];
            unsigned long long v =
                 (unsigned long long)f2bf(f0)
               | ((unsigned long long)f2bf(f1) << 16)
               | ((unsigned long long)f2bf(f2) << 32)
               | ((unsigned long long)f2bf(f3) << 48);
            __hip_atomic_store(&hx[((size_t)(t & 1) * 64 + s_s) * 128 + b * 4 + s_p],
                               v, __ATOMIC_RELAXED, __HIP_MEMORY_SCOPE_AGENT);
        }
        __syncthreads();                // compiler drains vmcnt before s_barrier
        if (tid == 0)
            __hip_atomic_store(&flags[b], (unsigned)(t + 1), __ATOMIC_RELEASE,
                               __HIP_MEMORY_SCOPE_AGENT);
    }
}

// ---------------- K7: MFMA logits + fixed-ref softmax partial sums ------------
__global__ __launch_bounds__(256, 1) void logits_mfma(
    const ushort* __restrict__ prec16, const ushort* __restrict__ score16,
    const float* __restrict__ debias, const int* __restrict__ colv,
    const unsigned char* __restrict__ reject,
    float* __restrict__ s_glob, float* __restrict__ label_glob)
{
    int i  = blockIdx.x >> 2;
    int cs = blockIdx.x & 3;
    int lane = threadIdx.x & 63;
    int w    = threadIdx.x >> 6;
    int l15  = lane & 15, quad = lane >> 4;

    bf16x8 afrag[2][16];
    bool live1 = (w < 3);                       // tile 7 skipped
    {
        int r0 = i * SEQL + (2 * w) * 16 + l15;
        const ushort* ap = prec16 + (size_t)r0 * DIM + quad * 8;
#pragma unroll
        for (int c = 0; c < 16; ++c) afrag[0][c] = *(const bf16x8*)(ap + c * 32);
    }
    if (live1) {
        int r1 = i * SEQL + (2 * w + 1) * 16 + l15;
        const ushort* ap = prec16 + (size_t)r1 * DIM + quad * 8;
#pragma unroll
        for (int c = 0; c < 16; ++c) afrag[1][c] = *(const bf16x8*)(ap + c * 32);
    }

    const unsigned char* rej = reject + (size_t)i * NCOLS;
    float srun0[4] = {0.f, 0.f, 0.f, 0.f};
    float srun1[4] = {0.f, 0.f, 0.f, 0.f};
    int n_base = cs * 1616;

    for (int st = 0; st < 101; ++st) {
        int n = n_base + st * 16 + l15;
        const ushort* bp = score16 + (size_t)n * DIM + quad * 8;
        f32x4 acc0 = {0.f, 0.f, 0.f, 0.f};
        f32x4 acc1 = {0.f, 0.f, 0.f, 0.f};
#pragma unroll
        for (int c = 0; c < 16; ++c) {
            bf16x8 b = *(const bf16x8*)(bp + c * 32);
            acc0 = __builtin_amdgcn_mfma_f32_16x16x32_bf16(afrag[0][c], b, acc0, 0, 0, 0);
            if (live1)
                acc1 = __builtin_amdgcn_mfma_f32_16x16x32_bf16(afrag[1][c], b, acc1, 0, 0, 0);
        }
        float db = debias[n];
        int   cv = colv[n];
        int   rj = rej[n];
        int   jj = n - i * L1P - 1;
        {
            int rowb = (2 * w) * 16 + quad * 4;
#pragma unroll
            for (int p = 0; p < 4; ++p) {
                int j = rowb + p;
                float l = acc0[p] - db;
                bool is_t = (j == jj);
                bool msk = (cv == 0) || (rj && !is_t);
                l = msk ? MASKV : l;
                if (is_t && j < SEQL) label_glob[i * SEQL + j] = l;
                if (j < SEQL) srun0[p] += __expf(l - M0);
            }
        }
        if (live1) {
            int rowb = (2 * w + 1) * 16 + quad * 4;
#pragma unroll
            for (int p = 0; p < 4; ++p) {
                int j = rowb + p;
                float l = acc1[p] - db;
                bool is_t = (j == jj);
                bool msk = (cv == 0) || (rj && !is_t);
                l = msk ? MASKV : l;
                if (is_t && j < SEQL) label_glob[i * SEQL + j] = l;
                if (j < SEQL) srun1[p] += __expf(l - M0);
            }
        }
    }
#pragma unroll
    for (int p = 0; p < 4; ++p) {
        float s = srun0[p];
        s += __shfl_xor(s, 1); s += __shfl_xor(s, 2);
        s += __shfl_xor(s, 4); s += __shfl_xor(s, 8);
        if (l15 == 0) {
            int j = (2 * w) * 16 + quad * 4 + p;
            if (j < SEQL) atomicAdd(&s_glob[i * SEQL + j], s);
        }
    }
    if (live1) {
#pragma unroll
        for (int p = 0; p < 4; ++p) {
            float s = srun1[p];
            s += __shfl_xor(s, 1); s += __shfl_xor(s, 2);
            s += __shfl_xor(s, 4); s += __shfl_xor(s, 8);
            if (l15 == 0) {
                int j = (2 * w + 1) * 16 + quad * 4 + p;
                if (j < SEQL) atomicAdd(&s_glob[i * SEQL + j], s);
            }
        }
    }
}

// ---------------- K8: per-row NLL + weighted sum ------------------------------
__global__ void nll_reduce(const float* __restrict__ s_glob, const float* __restrict__ label_glob,
                           const int* __restrict__ lmask, float* __restrict__ acc)
{
    int r = blockIdx.x * 256 + threadIdx.x;
    float v = 0.f, wt = 0.f;
    if (r < NROWS) {
        wt = (lmask[r] != 0) ? 1.f : 0.f;
        v  = (M0 + __logf(s_glob[r]) - label_glob[r]) * wt;
    }
#pragma unroll
    for (int o = 32; o; o >>= 1) { v += __shfl_down(v, o); wt += __shfl_down(wt, o); }
    if ((threadIdx.x & 63) == 0) { atomicAdd(&acc[0], v); atomicAdd(&acc[1], wt); }
}

// ---------------- K9: finalize ------------------------------------------------
__global__ void finalize(const float* __restrict__ acc, float* __restrict__ out)
{
    out[0] = acc[0] / fmaxf(acc[1], 1.f);
}

extern "C" void kernel_launch(void* const* d_in, const int* in_sizes, int n_in,
                              void* d_out, int out_size, void* d_ws, size_t ws_size,
                              hipStream_t stream)
{
    const int*   ids   = (const int*)d_in[0];
    const int*   lmask = (const int*)d_in[1];
    const float* pop   = (const float*)d_in[2];
    const float* emb   = (const float*)d_in[3];
    const float* W_ih  = (const float*)d_in[4];
    const float* W_hh  = (const float*)d_in[5];
    const float* b_ih  = (const float*)d_in[6];
    const float* b_hh  = (const float*)d_in[7];
    float* out = (float*)d_out;

    // workspace layout (~58 MB)
    ushort* score16 = (ushort*)d_ws;                               // 6464*512 bf16
    ushort* prec16  = score16 + (size_t)NCOLS * DIM;               // 6416*512 bf16 (incl pad)
    ushort* WT      = prec16 + (size_t)(NROWS + 16) * DIM;         // 1536*512 bf16 (W_hh^T)
    ushort* WIT     = WT + (size_t)D3 * DIM;                       // 1536*512 bf16 (W_ih^T)
    float*  debias  = (float*)(WIT + (size_t)D3 * DIM);            // 6464 f32
    int*    colv    = (int*)(debias + NCOLS);                      // 6464 i32
    unsigned char* rej = (unsigned char*)(colv + NCOLS);           // 64*6464 u8
    float*  gates   = (float*)(rej + (size_t)BSZ * NCOLS + 64);    // 6400*1536 f32
    float*  s_glob  = gates + (size_t)NROWS * D3;                  // 6400 f32
    float*  label_g = s_glob + NROWS;                              // 6400 f32
    float*  acc     = label_g + NROWS;                             // 2 f32
    unsigned* flags = (unsigned*)(acc + 2);                        // 32 u32
    unsigned long long* hx =
        (unsigned long long*)(((uintptr_t)(flags + 32) + 15) & ~(uintptr_t)15); // 2*64*128 u64

    init_ws<<<25, 256, 0, stream>>>(s_glob, acc, (unsigned*)(prec16 + (size_t)NROWS * DIM), flags);
    gather_embs<<<(NCOLS * 128) / 256, 256, 0, stream>>>(ids, emb, score16);
    aux_kernel<<<(NCOLS + 255) / 256, 256, 0, stream>>>(ids, pop, lmask, debias, colv);
    build_reject<<<dim3((NCOLS + 255) / 256, BSZ), 256, 0, stream>>>(ids, rej);
    wt_kernel<<<D3, DIM, 0, stream>>>(W_hh, WT);
    wt_kernel<<<D3, DIM, 0, stream>>>(W_ih, WIT);
    gates_mfma<<<dim3(24, 100), 256, 0, stream>>>(score16, WIT, b_ih, gates);
    gru_mfma<<<GRU_NB, 256, 0, stream>>>(WT, b_hh, gates, prec16, hx, flags);
    logits_mfma<<<BSZ * 4, 256, 0, stream>>>(prec16, score16, debias, colv, rej, s_glob, label_g);
    nll_reduce<<<(NROWS + 255) / 256, 256, 0, stream>>>(s_glob, label_g, lmask, acc);
    finalize<<<1, 1, 0, stream>>>(acc, out);
}

// Round 6
// 1314.548 us; speedup vs baseline: 10.7568x; 1.0971x over previous
//
#include <hip/hip_runtime.h>
#include <hip/hip_bf16.h>

#define BSZ   64
#define SEQL  100
#define DIM   512
#define L1P   101
#define NCOLS 6464     // BSZ*L1P
#define NROWS 6400     // BSZ*SEQL
#define D3    1536
#define MASKV -10000.0f
#define M0    16.0f    // fixed softmax reference: logits provably < ~10
#define GRU_NB 32      // persistent GRU blocks (32 << 256 CUs -> co-resident)

typedef __attribute__((ext_vector_type(8))) short bf16x8;
typedef __attribute__((ext_vector_type(4))) float f32x4;

__device__ __forceinline__ float sigm(float x)  { return 1.f / (1.f + __expf(-x)); }
__device__ __forceinline__ float ftanh(float x) { float e = __expf(2.f * x); return 1.f - 2.f / (e + 1.f); }
__device__ __forceinline__ ushort f2bf(float x) {
    __hip_bfloat16 b = __float2bfloat16(x);
    return *(ushort*)&b;
}

// ---------------- K0: init workspace ------------------------------------------
__global__ void init_ws(float* s_glob, float* acc, unsigned* prec_pad, unsigned* flags)
{
    int t = blockIdx.x * 256 + threadIdx.x;     // 6400 threads
    if (t < NROWS) s_glob[t] = 0.f;
    if (t < 2) acc[t] = 0.f;
    if (t < 4096) prec_pad[t] = 0;              // rows 6400..6415 of prec16
    if (t < GRU_NB) flags[t] = 0u;              // GRU step flags
}

// ---------------- K1: gather score16[k][:] = bf16(id_emb[ids[k]][:]) ----------
__global__ void gather_embs(const int* __restrict__ ids, const float* __restrict__ emb,
                            ushort* __restrict__ score16)
{
    int idx = blockIdx.x * 256 + threadIdx.x;   // 6464*128
    int row = idx >> 7, c4 = idx & 127;
    int id = ids[row];
    float4 v = *(const float4*)&emb[(size_t)id * DIM + c4 * 4];
    ushort4 u;
    u.x = f2bf(v.x); u.y = f2bf(v.y); u.z = f2bf(v.z); u.w = f2bf(v.w);
    *(ushort4*)&score16[(size_t)row * DIM + c4 * 4] = u;
}

// ---------------- K2: debias + col_valid --------------------------------------
__global__ void aux_kernel(const int* __restrict__ ids, const float* __restrict__ pop,
                           const int* __restrict__ lmask,
                           float* __restrict__ debias, int* __restrict__ colv)
{
    int k = blockIdx.x * 256 + threadIdx.x;
    if (k >= NCOLS) return;
    int id = ids[k];
    debias[k] = __logf(pop[id]);
    int j = k % L1P;
    colv[k] = (j == SEQL) ? 1 : lmask[(k / L1P) * SEQL + j];
}

// ---------------- K3: reject[i][k] = ids[k] in sample i's list ----------------
__global__ void build_reject(const int* __restrict__ ids, unsigned char* __restrict__ reject)
{
    __shared__ int s_ids[L1P];
    int i = blockIdx.y;
    int tid = threadIdx.x;
    if (tid < L1P) s_ids[tid] = ids[i * L1P + tid];
    __syncthreads();
    int k = blockIdx.x * 256 + tid;
    if (k >= NCOLS) return;
    int myid = ids[k];
    int rej = 0;
    for (int j = 0; j < L1P; ++j) rej |= (myid == s_ids[j]);
    reject[(size_t)i * NCOLS + k] = (unsigned char)rej;
}

// ---------------- K4: tiled transpose WT[c][k] = bf16(W[k][c]) ----------------
// grid (24, 8): 64x64 tiles of the 512x1536 source. Coalesced on both sides.
__global__ __launch_bounds__(256) void wt_tile(const float* __restrict__ W,
                                               ushort* __restrict__ WT)
{
    __shared__ float tile[64][65];
    int c0 = blockIdx.x * 64, k0 = blockIdx.y * 64;
    int tx = threadIdx.x & 63, ty = threadIdx.x >> 6;
    for (int r = ty; r < 64; r += 4)
        tile[r][tx] = W[(size_t)(k0 + r) * D3 + c0 + tx];
    __syncthreads();
    for (int r = ty; r < 64; r += 4)
        WT[(size_t)(c0 + r) * DIM + k0 + tx] = f2bf(tile[tx][r]);
}

// ---------------- K5: gates_x = x @ W_ih + b_ih  via MFMA ---------------------
__global__ __launch_bounds__(256) void gates_mfma(
    const ushort* __restrict__ score16, const ushort* __restrict__ WIT,
    const float* __restrict__ b_ih, float* __restrict__ gates)
{
    int n0 = blockIdx.x * 64, r0 = blockIdx.y * 64;
    int tid = threadIdx.x;
    int w = tid >> 6, lane = tid & 63, l15 = lane & 15, quad = lane >> 4;
    int r = r0 + w * 16 + l15;                  // gates row = sample*100 + step
    int i = r / SEQL, j = r % SEQL;
    const ushort* ap = score16 + (size_t)(i * L1P + j) * DIM + quad * 8;
    bf16x8 af[16];
#pragma unroll
    for (int c = 0; c < 16; ++c) af[c] = *(const bf16x8*)(ap + c * 32);

    f32x4 acc[4] = {{0,0,0,0},{0,0,0,0},{0,0,0,0},{0,0,0,0}};
#pragma unroll
    for (int c = 0; c < 16; ++c) {
#pragma unroll
        for (int nt = 0; nt < 4; ++nt) {
            const ushort* bp = WIT + (size_t)(n0 + nt * 16 + l15) * DIM + quad * 8 + c * 32;
            bf16x8 bb = *(const bf16x8*)bp;
            acc[nt] = __builtin_amdgcn_mfma_f32_16x16x32_bf16(af[c], bb, acc[nt], 0, 0, 0);
        }
    }
#pragma unroll
    for (int nt = 0; nt < 4; ++nt) {
        int n = n0 + nt * 16 + l15;
        float bi = b_ih[n];
#pragma unroll
        for (int p = 0; p < 4; ++p) {
            int rr = r0 + w * 16 + quad * 4 + p;
            gates[(size_t)rr * D3 + n] = acc[nt][p] + bi;
        }
    }
}

// ---------------- K6: batch-wide persistent MFMA GRU --------------------------
// 32 blocks x 256 thr. Block b owns dims [b*16, b*16+16); W-slab (48x512) in
// LDS for all 100 steps. Exchange: h(t) published into prec16 itself via
// packed-u64 sc1 (agent-scope, L2-bypass -> LLC) atomic stores; per-block flag
// release after the compiler's pre-barrier vmcnt drain. Readers spin on the 32
// flags (relaxed loads) then fetch A-frags with PLAIN pipelined 16B loads:
// every prec16 address is written exactly once per launch and only demand-
// filled into L1/L2 after its flag is seen, so cached reads are safe (launch-
// begin acquire clears cross-launch stale lines).
__global__ __launch_bounds__(256) void gru_mfma(
    const ushort* __restrict__ WT,      // [1536][512] bf16 = W_hh^T
    const float* __restrict__ b_hh,
    const float* __restrict__ gates,    // [6400][1536] f32 (includes b_ih)
    ushort* __restrict__ prec16,        // [(6400+16)][512] bf16 per-step h
    unsigned* __restrict__ flags)       // [32]
{
    __shared__ ushort Wslab[48][520];
    __shared__ float  hsl[64][17];      // f32 h for this block's 16 dims
    int b = blockIdx.x;
    int tid = threadIdx.x;
    int w = tid >> 6, lane = tid & 63, l15 = lane & 15, quad = lane >> 4;

    for (int row = w; row < 48; row += 4) {
        int g = row >> 4, c = row & 15;
        const ushort* src = WT + (size_t)(g * 512 + b * 16 + c) * DIM;
        *(bf16x8*)&Wslab[row][lane * 8] = *(const bf16x8*)(src + lane * 8);
    }
    for (int idx = tid; idx < 64 * 16; idx += 256) hsl[idx >> 4][idx & 15] = 0.f;
    __syncthreads();

    int d = b * 16 + l15;               // this thread's global dim
    float bhr = b_hh[d], bhz = b_hh[512 + d], bhn = b_hh[1024 + d];
    int s_s = tid >> 2, s_p = tid & 3;  // publish phase: sample, 4-dim group

    for (int t = 0; t < SEQL; ++t) {
        // prefetch gates for step t (independent of h) - in flight during spin
        float xr[4], xz[4], xn[4];
#pragma unroll
        for (int p = 0; p < 4; ++p) {
            int ss = w * 16 + quad * 4 + p;
            const float* gx = gates + ((size_t)ss * SEQL + t) * D3;
            xr[p] = gx[d]; xz[p] = gx[512 + d]; xn[p] = gx[1024 + d];
        }
        f32x4 acc[3] = {{0,0,0,0},{0,0,0,0},{0,0,0,0}};
        if (t > 0) {
            if (tid < GRU_NB) {
                unsigned tgt = (unsigned)t;
                while (__hip_atomic_load(&flags[tid], __ATOMIC_RELAXED,
                                         __HIP_MEMORY_SCOPE_AGENT) < tgt)
                    __builtin_amdgcn_s_sleep(1);
            }
            __syncthreads();            // orders every wave's A-loads after spin
            int sm = w * 16 + l15;
            const ushort* ap = prec16 + ((size_t)sm * SEQL + (t - 1)) * DIM + quad * 8;
            bf16x8 af[16];
#pragma unroll
            for (int c = 0; c < 16; ++c) af[c] = *(const bf16x8*)(ap + c * 32);
#pragma unroll
            for (int c = 0; c < 16; ++c) {
#pragma unroll
                for (int g = 0; g < 3; ++g) {
                    bf16x8 bb = *(const bf16x8*)&Wslab[g * 16 + l15][c * 32 + quad * 8];
                    acc[g] = __builtin_amdgcn_mfma_f32_16x16x32_bf16(af[c], bb, acc[g], 0, 0, 0);
                }
            }
        }
        // epilogue: 4 samples/thread (C layout: col=l15=dim, row=quad*4+p=sample)
#pragma unroll
        for (int p = 0; p < 4; ++p) {
            int ss = w * 16 + quad * 4 + p;
            float r = sigm(xr[p] + acc[0][p] + bhr);
            float z = sigm(xz[p] + acc[1][p] + bhz);
            float n = ftanh(xn[p] + r * (acc[2][p] + bhn));
            float hnew = (1.f - z) * n + z * hsl[ss][l15];
            hsl[ss][l15] = hnew;
        }
        __syncthreads();                // hsl writes visible to publish phase
        {
            float f0 = hsl[s_s][s_p * 4 + 0], f1 = hsl[s_s][s_p * 4 + 1];
            float f2 = hsl[s_s][s_p * 4 + 2], f3 = hsl[s_s][s_p * 4 + 3];
            unsigned long long v =
                 (unsigned long long)f2bf(f0)
               | ((unsigned long long)f2bf(f1) << 16)
               | ((unsigned long long)f2bf(f2) << 32)
               | ((unsigned long long)f2bf(f3) << 48);
            unsigned long long* dst = (unsigned long long*)prec16 +
                (((size_t)s_s * SEQL + t) * DIM + b * 16 + s_p * 4) / 4;
            __hip_atomic_store(dst, v, __ATOMIC_RELAXED, __HIP_MEMORY_SCOPE_AGENT);
        }
        __syncthreads();                // compiler drains vmcnt before s_barrier
        if (tid == 0)
            __hip_atomic_store(&flags[b], (unsigned)(t + 1), __ATOMIC_RELEASE,
                               __HIP_MEMORY_SCOPE_AGENT);
    }
}

// ---------------- K7: MFMA logits + fixed-ref softmax partial sums ------------
__global__ __launch_bounds__(256, 1) void logits_mfma(
    const ushort* __restrict__ prec16, const ushort* __restrict__ score16,
    const float* __restrict__ debias, const int* __restrict__ colv,
    const unsigned char* __restrict__ reject,
    float* __restrict__ s_glob, float* __restrict__ label_glob)
{
    int i  = blockIdx.x >> 2;
    int cs = blockIdx.x & 3;
    int lane = threadIdx.x & 63;
    int w    = threadIdx.x >> 6;
    int l15  = lane & 15, quad = lane >> 4;

    bf16x8 afrag[2][16];
    bool live1 = (w < 3);                       // tile 7 skipped
    {
        int r0 = i * SEQL + (2 * w) * 16 + l15;
        const ushort* ap = prec16 + (size_t)r0 * DIM + quad * 8;
#pragma unroll
        for (int c = 0; c < 16; ++c) afrag[0][c] = *(const bf16x8*)(ap + c * 32);
    }
    if (live1) {
        int r1 = i * SEQL + (2 * w + 1) * 16 + l15;
        const ushort* ap = prec16 + (size_t)r1 * DIM + quad * 8;
#pragma unroll
        for (int c = 0; c < 16; ++c) afrag[1][c] = *(const bf16x8*)(ap + c * 32);
    }

    const unsigned char* rej = reject + (size_t)i * NCOLS;
    float srun0[4] = {0.f, 0.f, 0.f, 0.f};
    float srun1[4] = {0.f, 0.f, 0.f, 0.f};
    int n_base = cs * 1616;

    for (int st = 0; st < 101; ++st) {
        int n = n_base + st * 16 + l15;
        const ushort* bp = score16 + (size_t)n * DIM + quad * 8;
        f32x4 acc0 = {0.f, 0.f, 0.f, 0.f};
        f32x4 acc1 = {0.f, 0.f, 0.f, 0.f};
#pragma unroll
        for (int c = 0; c < 16; ++c) {
            bf16x8 b = *(const bf16x8*)(bp + c * 32);
            acc0 = __builtin_amdgcn_mfma_f32_16x16x32_bf16(afrag[0][c], b, acc0, 0, 0, 0);
            if (live1)
                acc1 = __builtin_amdgcn_mfma_f32_16x16x32_bf16(afrag[1][c], b, acc1, 0, 0, 0);
        }
        float db = debias[n];
        int   cv = colv[n];
        int   rj = rej[n];
        int   jj = n - i * L1P - 1;
        {
            int rowb = (2 * w) * 16 + quad * 4;
#pragma unroll
            for (int p = 0; p < 4; ++p) {
                int j = rowb + p;
                float l = acc0[p] - db;
                bool is_t = (j == jj);
                bool msk = (cv == 0) || (rj && !is_t);
                l = msk ? MASKV : l;
                if (is_t && j < SEQL) label_glob[i * SEQL + j] = l;
                if (j < SEQL) srun0[p] += __expf(l - M0);
            }
        }
        if (live1) {
            int rowb = (2 * w + 1) * 16 + quad * 4;
#pragma unroll
            for (int p = 0; p < 4; ++p) {
                int j = rowb + p;
                float l = acc1[p] - db;
                bool is_t = (j == jj);
                bool msk = (cv == 0) || (rj && !is_t);
                l = msk ? MASKV : l;
                if (is_t && j < SEQL) label_glob[i * SEQL + j] = l;
                if (j < SEQL) srun1[p] += __expf(l - M0);
            }
        }
    }
#pragma unroll
    for (int p = 0; p < 4; ++p) {
        float s = srun0[p];
        s += __shfl_xor(s, 1); s += __shfl_xor(s, 2);
        s += __shfl_xor(s, 4); s += __shfl_xor(s, 8);
        if (l15 == 0) {
            int j = (2 * w) * 16 + quad * 4 + p;
            if (j < SEQL) atomicAdd(&s_glob[i * SEQL + j], s);
        }
    }
    if (live1) {
#pragma unroll
        for (int p = 0; p < 4; ++p) {
            float s = srun1[p];
            s += __shfl_xor(s, 1); s += __shfl_xor(s, 2);
            s += __shfl_xor(s, 4); s += __shfl_xor(s, 8);
            if (l15 == 0) {
                int j = (2 * w + 1) * 16 + quad * 4 + p;
                if (j < SEQL) atomicAdd(&s_glob[i * SEQL + j], s);
            }
        }
    }
}

// ---------------- K8: per-row NLL + weighted sum ------------------------------
__global__ void nll_reduce(const float* __restrict__ s_glob, const float* __restrict__ label_glob,
                           const int* __restrict__ lmask, float* __restrict__ acc)
{
    int r = blockIdx.x * 256 + threadIdx.x;
    float v = 0.f, wt = 0.f;
    if (r < NROWS) {
        wt = (lmask[r] != 0) ? 1.f : 0.f;
        v  = (M0 + __logf(s_glob[r]) - label_glob[r]) * wt;
    }
#pragma unroll
    for (int o = 32; o; o >>= 1) { v += __shfl_down(v, o); wt += __shfl_down(wt, o); }
    if ((threadIdx.x & 63) == 0) { atomicAdd(&acc[0], v); atomicAdd(&acc[1], wt); }
}

// ---------------- K9: finalize ------------------------------------------------
__global__ void finalize(const float* __restrict__ acc, float* __restrict__ out)
{
    out[0] = acc[0] / fmaxf(acc[1], 1.f);
}

extern "C" void kernel_launch(void* const* d_in, const int* in_sizes, int n_in,
                              void* d_out, int out_size, void* d_ws, size_t ws_size,
                              hipStream_t stream)
{
    const int*   ids   = (const int*)d_in[0];
    const int*   lmask = (const int*)d_in[1];
    const float* pop   = (const float*)d_in[2];
    const float* emb   = (const float*)d_in[3];
    const float* W_ih  = (const float*)d_in[4];
    const float* W_hh  = (const float*)d_in[5];
    const float* b_ih  = (const float*)d_in[6];
    const float* b_hh  = (const float*)d_in[7];
    float* out = (float*)d_out;

    // workspace layout (~57 MB)
    ushort* score16 = (ushort*)d_ws;                               // 6464*512 bf16
    ushort* prec16  = score16 + (size_t)NCOLS * DIM;               // 6416*512 bf16 (incl pad)
    ushort* WT      = prec16 + (size_t)(NROWS + 16) * DIM;         // 1536*512 bf16 (W_hh^T)
    ushort* WIT     = WT + (size_t)D3 * DIM;                       // 1536*512 bf16 (W_ih^T)
    float*  debias  = (float*)(WIT + (size_t)D3 * DIM);            // 6464 f32
    int*    colv    = (int*)(debias + NCOLS);                      // 6464 i32
    unsigned char* rej = (unsigned char*)(colv + NCOLS);           // 64*6464 u8
    float*  gates   = (float*)(rej + (size_t)BSZ * NCOLS + 64);    // 6400*1536 f32
    float*  s_glob  = gates + (size_t)NROWS * D3;                  // 6400 f32
    float*  label_g = s_glob + NROWS;                              // 6400 f32
    float*  acc     = label_g + NROWS;                             // 2 f32
    unsigned* flags = (unsigned*)(acc + 2);                        // 32 u32

    init_ws<<<25, 256, 0, stream>>>(s_glob, acc, (unsigned*)(prec16 + (size_t)NROWS * DIM), flags);
    gather_embs<<<(NCOLS * 128) / 256, 256, 0, stream>>>(ids, emb, score16);
    aux_kernel<<<(NCOLS + 255) / 256, 256, 0, stream>>>(ids, pop, lmask, debias, colv);
    build_reject<<<dim3((NCOLS + 255) / 256, BSZ), 256, 0, stream>>>(ids, rej);
    wt_tile<<<dim3(24, 8), 256, 0, stream>>>(W_hh, WT);
    wt_tile<<<dim3(24, 8), 256, 0, stream>>>(W_ih, WIT);
    gates_mfma<<<dim3(24, 100), 256, 0, stream>>>(score16, WIT, b_ih, gates);
    gru_mfma<<<GRU_NB, 256, 0, stream>>>(WT, b_hh, gates, prec16, flags);
    logits_mfma<<<BSZ * 4, 256, 0, stream>>>(prec16, score16, debias, colv, rej, s_glob, label_g);
    nll_reduce<<<(NROWS + 255) / 256, 256, 0, stream>>>(s_glob, label_g, lmask, acc);
    finalize<<<1, 1, 0, stream>>>(acc, out);
}